// Round 1
// baseline (696.758 us; speedup 1.0000x reference)
//
#include <hip/hip_runtime.h>

typedef __attribute__((ext_vector_type(8))) short short8;
typedef __attribute__((ext_vector_type(4))) float f32x4;

#define CDIM   512
#define NROWS  81
#define IMG    (NROWS * CDIM)      // 41472 floats per image
#define PA     520                 // sA row pitch in bf16 (512 + 8 pad)
#define PQ     264                 // sQ row pitch in bf16 (256 + 8 pad)

// LDS byte offsets (all 16B-aligned)
#define SA_BYTES   (NROWS * PA * 2)            // 84240
#define SQ_OFFB    84240
#define SQ_BYTES   (NROWS * PQ * 2)            // 42768
#define SPART_OFFB 127008                      // 8 waves * 256 f32 = 8192 B
#define SATTN_OFFB 135200
#define ST2_OFFB   135584
#define SWGT_OFFB  135968
#define SMEM_BYTES 136352

__device__ __forceinline__ unsigned short f2bf(float f) {
    unsigned int u = __float_as_uint(f);
    u += 0x7fffu + ((u >> 16) & 1u);   // round-to-nearest-even
    return (unsigned short)(u >> 16);
}
__device__ __forceinline__ float bf2f(unsigned short s) {
    return __uint_as_float(((unsigned int)s) << 16);
}

extern "C" __global__ void __launch_bounds__(512, 1)
attn_kernel(const float* __restrict__ x, const float* __restrict__ Wfc,
            const float* __restrict__ bfc, float* __restrict__ out)
{
    extern __shared__ char smem[];
    unsigned short* sA   = (unsigned short*)(smem);
    unsigned short* sQ   = (unsigned short*)(smem + SQ_OFFB);
    float*          sPart = (float*)(smem + SPART_OFFB);
    float*          sAttn = (float*)(smem + SATTN_OFFB);
    float*          sT2   = (float*)(smem + ST2_OFFB);
    float*          sWgt  = (float*)(smem + SWGT_OFFB);

    const int tid  = threadIdx.x;
    const int wave = tid >> 6;
    const int lane = tid & 63;
    const int r15  = lane & 15;
    const int q    = lane >> 4;
    const long img = blockIdx.x;
    const float* xin = x + img * (long)IMG;

    // ---------- Phase 1: stage x -> sA as bf16, rows indexed by np = n*9+p ----------
    for (int it = 0; it < 11; ++it) {
        int row = it * 8 + wave;
        if (row < NROWS) {
            int n = row / 9, p = row % 9;
            int h  = (n / 3) * 3 + p / 3;
            int w2 = (n % 3) * 3 + p % 3;
            const float* src = xin + (h * 9 + w2) * CDIM + lane * 8;
            f32x4 v0 = *(const f32x4*)src;
            f32x4 v1 = *(const f32x4*)(src + 4);
            short8 pk;
            pk[0] = (short)f2bf(v0[0]); pk[1] = (short)f2bf(v0[1]);
            pk[2] = (short)f2bf(v0[2]); pk[3] = (short)f2bf(v0[3]);
            pk[4] = (short)f2bf(v1[0]); pk[5] = (short)f2bf(v1[1]);
            pk[6] = (short)f2bf(v1[2]); pk[7] = (short)f2bf(v1[3]);
            *(short8*)&sA[row * PA + lane * 8] = pk;
        }
    }
    __syncthreads();

    // ---------- Phase 2: xq = x_fc @ W^T + b  (M=81->96, N=256, K=512) ----------
    // wave handles output cols [32*wave, 32*wave+32)
    f32x4 acc[6][2];
    #pragma unroll
    for (int i = 0; i < 6; ++i) {
        acc[i][0] = (f32x4){0.f, 0.f, 0.f, 0.f};
        acc[i][1] = (f32x4){0.f, 0.f, 0.f, 0.f};
    }
    const float bias0 = bfc[wave * 32 + r15];
    const float bias1 = bfc[wave * 32 + 16 + r15];
    const float* wrow0 = Wfc + (long)(wave * 32 + r15) * CDIM + q * 8;
    const float* wrow1 = wrow0 + 16 * CDIM;

    #pragma unroll 4
    for (int ks = 0; ks < 16; ++ks) {
        // B-fragments: W^T[k][n] = W[n][k]; contiguous in k -> fp32 loads + convert
        const float* s0 = wrow0 + ks * 32;
        const float* s1 = wrow1 + ks * 32;
        f32x4 u0 = *(const f32x4*)s0, u1 = *(const f32x4*)(s0 + 4);
        f32x4 u2 = *(const f32x4*)s1, u3 = *(const f32x4*)(s1 + 4);
        short8 b0, b1;
        b0[0] = (short)f2bf(u0[0]); b0[1] = (short)f2bf(u0[1]);
        b0[2] = (short)f2bf(u0[2]); b0[3] = (short)f2bf(u0[3]);
        b0[4] = (short)f2bf(u1[0]); b0[5] = (short)f2bf(u1[1]);
        b0[6] = (short)f2bf(u1[2]); b0[7] = (short)f2bf(u1[3]);
        b1[0] = (short)f2bf(u2[0]); b1[1] = (short)f2bf(u2[1]);
        b1[2] = (short)f2bf(u2[2]); b1[3] = (short)f2bf(u2[3]);
        b1[4] = (short)f2bf(u3[0]); b1[5] = (short)f2bf(u3[1]);
        b1[6] = (short)f2bf(u3[2]); b1[7] = (short)f2bf(u3[3]);
        #pragma unroll
        for (int mt = 0; mt < 6; ++mt) {
            int rowA = mt * 16 + r15;
            if (rowA > 80) rowA = 80;                 // mt=5 tail: harmless dup
            short8 a = *(short8*)&sA[rowA * PA + ks * 32 + q * 8];
            acc[mt][0] = __builtin_amdgcn_mfma_f32_16x16x32_bf16(a, b0, acc[mt][0], 0, 0, 0);
            acc[mt][1] = __builtin_amdgcn_mfma_f32_16x16x32_bf16(a, b1, acc[mt][1], 0, 0, 0);
        }
    }
    // epilogue: + bias, -> sQ bf16. C/D layout: col=lane&15, row=q*4+reg
    #pragma unroll
    for (int mt = 0; mt < 6; ++mt) {
        #pragma unroll
        for (int nt = 0; nt < 2; ++nt) {
            int col = wave * 32 + nt * 16 + r15;
            float bb = nt ? bias1 : bias0;
            #pragma unroll
            for (int r = 0; r < 4; ++r) {
                int row = mt * 16 + q * 4 + r;
                if (row < NROWS)
                    sQ[row * PQ + col] = f2bf(acc[mt][nt][r] + bb);
            }
        }
    }
    __syncthreads();

    // ---------- Phase 3: attn partials = sum_p Q_p Q_p^T via mfma(a,a) ----------
    f32x4 qacc = (f32x4){0.f, 0.f, 0.f, 0.f};
    for (int p = wave; p < 9; p += 8) {
        int rq = r15 * 9 + p;
        if (rq > 80) rq = 80;                         // rows n>=9 are ignored
        const unsigned short* qrow = &sQ[rq * PQ + q * 8];
        #pragma unroll
        for (int ks = 0; ks < 8; ++ks) {
            short8 f = *(short8*)&qrow[ks * 32];
            qacc = __builtin_amdgcn_mfma_f32_16x16x32_bf16(f, f, qacc, 0, 0, 0);
        }
    }
    {
        float* pp = &sPart[wave * 256];
        #pragma unroll
        for (int r = 0; r < 4; ++r)
            pp[(q * 4 + r) * 16 + r15] = qacc[r];
    }
    __syncthreads();

    // ---------- Phase 4: softmax chain (fp32, tiny) ----------
    if (tid < 81) {
        int n = tid / 9, m = tid % 9;
        float s = 0.f;
        #pragma unroll
        for (int w = 0; w < 8; ++w) s += sPart[w * 256 + n * 16 + m];
        s *= (1.0f / 48.0f);                          // (hidden*P)^-0.5
        if (n == m) s -= 100.0f;                      // diagonal mask
        sAttn[tid] = s;
    }
    __syncthreads();
    if (tid < 81) {
        int n = tid / 9, k = tid % 9;
        float s = 0.f;
        #pragma unroll
        for (int m = 0; m < 9; ++m) s += sAttn[n * 9 + m] * sAttn[k * 9 + m];
        sT2[tid] = s * (1.0f / 3.0f);                 // N^-0.5
    }
    __syncthreads();
    if (tid < 9) {
        int n = tid;
        float t[9], mx = -1e30f;
        #pragma unroll
        for (int m = 0; m < 9; ++m) { t[m] = sT2[n * 9 + m]; mx = fmaxf(mx, t[m]); }
        float sum = 0.f;
        #pragma unroll
        for (int m = 0; m < 9; ++m) { t[m] = __expf(t[m] - mx); sum += t[m]; }
        float inv = 1.0f / sum;
        float g[9], mx2 = -1e30f;
        #pragma unroll
        for (int m = 0; m < 9; ++m) { g[m] = sAttn[n * 9 + m] + t[m] * inv; mx2 = fmaxf(mx2, g[m]); }
        float sum2 = 0.f;
        #pragma unroll
        for (int m = 0; m < 9; ++m) { g[m] = __expf(g[m] - mx2); sum2 += g[m]; }
        float inv2 = 1.0f / sum2;
        #pragma unroll
        for (int m = 0; m < 9; ++m) sWgt[n * 9 + m] = g[m] * inv2;
    }
    __syncthreads();

    // ---------- Phase 5: out rows = attn @ V, written in (h,w,c) order ----------
    for (int it = 0; it < 11; ++it) {
        int orow = it * 8 + wave;                     // orow = h*9 + w
        if (orow < NROWS) {
            int h = orow / 9, w2 = orow % 9;
            int n = (h / 3) * 3 + w2 / 3;
            int p = (h % 3) * 3 + w2 % 3;
            float av[8] = {0.f, 0.f, 0.f, 0.f, 0.f, 0.f, 0.f, 0.f};
            #pragma unroll
            for (int m = 0; m < 9; ++m) {
                float wt = sWgt[n * 9 + m];           // broadcast LDS read
                short8 v = *(short8*)&sA[(m * 9 + p) * PA + lane * 8];
                #pragma unroll
                for (int j = 0; j < 8; ++j)
                    av[j] += wt * bf2f((unsigned short)v[j]);
            }
            float* dst = out + img * (long)IMG + orow * CDIM + lane * 8;
            *(f32x4*)dst       = (f32x4){av[0], av[1], av[2], av[3]};
            *(f32x4*)(dst + 4) = (f32x4){av[4], av[5], av[6], av[7]};
        }
    }
}

extern "C" void kernel_launch(void* const* d_in, const int* in_sizes, int n_in,
                              void* d_out, int out_size, void* d_ws, size_t ws_size,
                              hipStream_t stream) {
    (void)in_sizes; (void)n_in; (void)d_ws; (void)ws_size; (void)out_size;
    const float* x   = (const float*)d_in[0];
    const float* Wfc = (const float*)d_in[1];
    const float* bfc = (const float*)d_in[2];
    float* o = (float*)d_out;
    // allow >64KB dynamic LDS (gfx950 has 160 KiB/CU); same call every launch
    hipFuncSetAttribute((const void*)attn_kernel,
                        hipFuncAttributeMaxDynamicSharedMemorySize, SMEM_BYTES);
    attn_kernel<<<dim3(2048), dim3(512), SMEM_BYTES, stream>>>(x, Wfc, bfc, o);
}